// Round 2
// baseline (103.001 us; speedup 1.0000x reference)
//
#include <hip/hip_runtime.h>
#include <math.h>

#define BSZ 4096
#define DIM 128
#define K_TOP 200
#define TGUESS 0.11f
#define HBINS 512         // linear bins over [0.1, 0.74), width 0.00125
#define EXPSCALE 1073741824.0f   // 2^30 fixed-point scale for packed exp sums
#define MASK40 0xFFFFFFFFFFull

typedef unsigned short u16;
typedef unsigned int u32;
typedef unsigned long long u64;
typedef __attribute__((ext_vector_type(8))) short bf16x8;
typedef __attribute__((ext_vector_type(4))) float floatx4;

__device__ inline u16 f2bf(float x) {  // fp32 -> bf16 RNE
    u32 u = __float_as_uint(x);
    return (u16)((u + 0x7fffu + ((u >> 16) & 1u)) >> 16);
}

// ---------------- pre: F -> bf16, and zero the global accumulators ----------------
__global__ __launch_bounds__(256) void pre_kernel(const float* __restrict__ F,
                                                  u16* __restrict__ Fb,
                                                  u32* __restrict__ gz) {
    int idx = blockIdx.x * 256 + threadIdx.x;
    if (blockIdx.x == 0 && threadIdx.x < 8) gz[threadIdx.x] = 0u;  // gd[2] (f64) + gcnt + pad
    if (idx < BSZ * DIM / 4) {
        float4 v = ((const float4*)F)[idx];
        ushort4 r;
        r.x = f2bf(v.x); r.y = f2bf(v.y); r.z = f2bf(v.z); r.w = f2bf(v.w);
        ((ushort4*)Fb)[idx] = r;
    }
}

// ---------------- fused kernel: GEMM + histogram-of-exp + top-k + loss + reduce ----------------
// Grid = 256 blocks (one/CU), 1024 threads = 16 waves. Block owns 16 anchor
// rows x all 4096 cols; wave w sweeps cols [w*256, w*256+256).
// R14 changes vs R13:
//  - reverted manual B prefetch (VGPR_Count=44 proved compiler defeated it;
//    R12's in-loop loads were >=7us faster).
//  - positives accumulate in REGISTERS (pps/ppe/ppc[4]) with a shfl_xor
//    reduce over the 16-lane l16 group -> 12 atomic instrs/wave instead of
//    ~2000 same-address contended LDS atomics per block.
//  - histogram (count, exp-sum) packed into ONE u64 LDS atomic per hot
//    negative: (1<<40) + (u32)(ex*2^30). Halves histogram atomic traffic.
//    Bounds: ex*2^30 < 2^27 for s<=0.74 tail; <=4096 entries -> sum < 2^39.
__global__ __launch_bounds__(1024) void fused_all(const u16* __restrict__ Fb,
                                                  const int* __restrict__ labels,
                                                  double* __restrict__ gd,   // [0]=pr sum, [1]=vd sum
                                                  u32* __restrict__ gcnt,
                                                  float* __restrict__ out) {
    __shared__ u64 hpk[16 * HBINS];            // 64 KB  [row][bin] packed (cnt<<40 | exp*2^30)
    __shared__ unsigned char labc[BSZ];        // 4 KB
    __shared__ float ps[16], pe[16], pc[16];
    __shared__ float prv[16], vdv[16];

    const int tid  = threadIdx.x;
    const int wave = tid >> 6, lane = tid & 63;
    const int l16  = lane & 15, quad = lane >> 4;
    const int brow = blockIdx.x * 16;

    // ---- init ----
    {
        int4 lv = ((const int4*)labels)[tid];          // BSZ/4 == 1024 == blockDim
        uchar4 r;
        r.x = (unsigned char)lv.x; r.y = (unsigned char)lv.y;
        r.z = (unsigned char)lv.z; r.w = (unsigned char)lv.w;
        ((uchar4*)labc)[tid] = r;
    }
    #pragma unroll
    for (int q = 0; q < 8; ++q) hpk[q * 1024 + tid] = 0ull;
    if (tid < 16) { ps[tid] = 0.f; pe[tid] = 0.f; pc[tid] = 0.f; }
    __syncthreads();

    // ---- A fragments in registers for the whole sweep ----
    const u16* Ab = Fb + (size_t)(brow + l16) * DIM + quad * 8;
    bf16x8 afr[4];
    #pragma unroll
    for (int ks = 0; ks < 4; ++ks) afr[ks] = *(const bf16x8*)(Ab + ks * 32);

    unsigned char labr_[4];
    #pragma unroll
    for (int e = 0; e < 4; ++e) labr_[e] = labc[brow + quad * 4 + e];

    // register accumulators for positives (rows quad*4+e)
    float pps[4] = {0.f, 0.f, 0.f, 0.f};
    float ppe[4] = {0.f, 0.f, 0.f, 0.f};
    float ppc[4] = {0.f, 0.f, 0.f, 0.f};

    // ---- phase 1: sweep 8 n-tiles of 32 cols ----
    for (int t = 0; t < 8; ++t) {
        const int tn0 = wave * 256 + t * 32;
        const u16* B0 = Fb + (size_t)(tn0 + l16) * DIM + quad * 8;
        const u16* B1 = Fb + (size_t)(tn0 + 16 + l16) * DIM + quad * 8;
        floatx4 a0 = (floatx4){0.f, 0.f, 0.f, 0.f};
        floatx4 a1 = (floatx4){0.f, 0.f, 0.f, 0.f};
        #pragma unroll
        for (int ks = 0; ks < 4; ++ks) {
            bf16x8 b0 = *(const bf16x8*)(B0 + ks * 32);
            bf16x8 b1 = *(const bf16x8*)(B1 + ks * 32);
            a0 = __builtin_amdgcn_mfma_f32_16x16x32_bf16(afr[ks], b0, a0, 0, 0, 0);
            a1 = __builtin_amdgcn_mfma_f32_16x16x32_bf16(afr[ks], b1, a1, 0, 0, 0);
        }
        // epilogue: C/D map col = l16 (B side), row = quad*4+e (A side) [m89/m91]
        #pragma unroll
        for (int nt = 0; nt < 2; ++nt) {
            const floatx4 accv = nt ? a1 : a0;
            const int cg_ = tn0 + nt * 16 + l16;       // global col
            const int lc = labc[cg_];
            #pragma unroll
            for (int e = 0; e < 4; ++e) {
                const int rl = quad * 4 + e;
                const int rg = brow + rl;
                if (cg_ == rg) continue;               // diagonal
                const float s = accv[e];
                const bool pos = (lc == (int)labr_[e]);  // positive (~41/row total)
                if (pos | (s > TGUESS)) {
                    const float ex = __expf((s - 1.f) * 10.f);
                    if (pos) {                         // register accumulate
                        pps[e] += s; ppe[e] += ex; ppc[e] += 1.f;
                    } else {                           // hard negative -> packed histogram
                        int b = (int)((s - 0.1f) * 800.f);
                        b = b < 0 ? 0 : (b > HBINS - 1 ? HBINS - 1 : b);
                        const u64 pk = (1ull << 40) + (u64)(u32)(ex * EXPSCALE);
                        atomicAdd(&hpk[rl * HBINS + b], pk);   // fire-and-forget
                    }
                }
            }
        }
    }

    // ---- fold positive partials: reduce over the 16-lane l16 group, 1 atomic/row/wave ----
    #pragma unroll
    for (int e = 0; e < 4; ++e) {
        float a = pps[e], b = ppe[e], c = ppc[e];
        #pragma unroll
        for (int off = 8; off; off >>= 1) {
            a += __shfl_xor(a, off);
            b += __shfl_xor(b, off);
            c += __shfl_xor(c, off);
        }
        if (l16 == 0) {
            const int rl = quad * 4 + e;
            atomicAdd(&ps[rl], a);
            atomicAdd(&pe[rl], b);
            atomicAdd(&pc[rl], c);
        }
    }
    __syncthreads();

    // ---- phase 2: wave r = threshold bin + loss for row r (wave-private) ----
    {
        const int r = wave;
        const u64* hp = hpk + r * HBINS;

        int local[8], csum = 0;                        // lane owns bins [lane*8, lane*8+8)
        float lx[8];
        #pragma unroll
        for (int t2 = 0; t2 < 8; ++t2) {
            const u64 v = hp[lane * 8 + t2];
            local[t2] = (int)(v >> 40);
            lx[t2] = (float)(v & MASK40) * (1.0f / EXPSCALE);
            csum += local[t2];
        }
        int suf = csum;
        #pragma unroll
        for (int off = 1; off < 64; off <<= 1) {       // wave suffix-sum
            int t2 = __shfl_down(suf, off);
            if (lane + off < 64) suf += t2;
        }
        const int above = suf - csum;
        const bool owner = (above < K_TOP) && (suf >= K_TOP);
        int b1o = 0, c1o = 0;
        if (owner) {
            int acc2 = above;
            #pragma unroll
            for (int t2 = 7; t2 >= 0; --t2) {
                if (acc2 + local[t2] >= K_TOP) { b1o = lane * 8 + t2; c1o = acc2; break; }
                acc2 += local[t2];
            }
        }
        unsigned long long bm = __ballot(owner);
        int b1, K2;
        if (bm == 0ull) {            // fewer than K_TOP candidates: take them all
            b1 = -1; K2 = 0;
        } else {
            const int src = __ffsll((long long)bm) - 1;
            b1 = __shfl(b1o, src);
            K2 = K_TOP - __shfl(c1o, src);
        }

        float te = 0.f;                                // exact exp-sum above bin b1
        #pragma unroll
        for (int t2 = 0; t2 < 8; ++t2) {
            const int b = lane * 8 + t2;
            if (b > b1) te += lx[t2];
        }
        #pragma unroll
        for (int off = 32; off; off >>= 1) te += __shfl_down(te, off);

        if (lane == 0) {
            float tsum = 0.f;
            if (K2 > 0) {                              // K2>0 implies b1 >= 0
                const u64 v = hp[b1];
                const int cb = (int)(v >> 40);
                if (cb > 0)                            // in-bin average
                    tsum = (float)K2 * ((float)(v & MASK40) * (1.0f / EXPSCALE)) / (float)cb;
            }
            const float pcnt = pc[r];
            const int labi = labc[brow + r];
            float pr = 0.f, vd = 0.f;
            if (labi > 0 && pcnt > 0.f) {
                float denom = pe[r] + te + tsum;
                float slp = 10.f * (ps[r] - pcnt) - pcnt * logf(denom);
                pr = -2.f * slp / pcnt;
                vd = 1.f;
            }
            prv[r] = pr; vdv[r] = vd;
        }
    }
    __syncthreads();

    // ---- folded reduction: block partial (deterministic order) -> f64 atomics ----
    if (tid == 0) {
        float sp = 0.f, sv = 0.f;
        #pragma unroll
        for (int r2 = 0; r2 < 16; ++r2) { sp += prv[r2]; sv += vdv[r2]; }
        atomicAdd(&gd[0], (double)sp);
        atomicAdd(&gd[1], (double)sv);
        __threadfence();
        u32 done = atomicAdd(gcnt, 1u);
        if (done == 255u) {                            // last block computes the ratio
            __threadfence();
            double a = atomicAdd(&gd[0], 0.0);
            double b = atomicAdd(&gd[1], 0.0);
            out[0] = (float)(a / b);
        }
    }
}

extern "C" void kernel_launch(void* const* d_in, const int* in_sizes, int n_in,
                              void* d_out, int out_size, void* d_ws, size_t ws_size,
                              hipStream_t stream) {
    const float* F      = (const float*)d_in[0];
    const int*   labels = (const int*)d_in[1];
    float*       out    = (float*)d_out;

    char* w = (char*)d_ws;
    u16*    Fb   = (u16*)w;                 w += (size_t)BSZ * DIM * 2;   // 1 MB
    double* gd   = (double*)w;                                            // 16 B
    u32*    gcnt = (u32*)(w + 16);                                        // 4 B (+pad)

    pre_kernel<<<512, 256, 0, stream>>>(F, Fb, (u32*)gd);
    fused_all<<<256, 1024, 0, stream>>>(Fb, labels, gd, gcnt, out);
}

// Round 3
// 94.421 us; speedup vs baseline: 1.0909x; 1.0909x over previous
//
#include <hip/hip_runtime.h>
#include <math.h>

#define BSZ 4096
#define DIM 128
#define K_TOP 200
#define TGUESS 0.11f
#define HBINS 512         // linear bins over [0.1, 0.74), width 0.00125
#define EXPSCALE 1073741824.0f   // 2^30 fixed-point scale for packed exp sums
#define MASK40 0xFFFFFFFFFFull

typedef unsigned short u16;
typedef unsigned int u32;
typedef unsigned long long u64;
typedef __attribute__((ext_vector_type(8))) short bf16x8;
typedef __attribute__((ext_vector_type(4))) float floatx4;

__device__ inline u16 f2bf(float x) {  // fp32 -> bf16 RNE
    u32 u = __float_as_uint(x);
    return (u16)((u + 0x7fffu + ((u >> 16) & 1u)) >> 16);
}

// ---------------- pre: F -> bf16 ----------------
__global__ __launch_bounds__(256) void pre_kernel(const float* __restrict__ F,
                                                  u16* __restrict__ Fb) {
    int idx = blockIdx.x * 256 + threadIdx.x;
    if (idx < BSZ * DIM / 4) {
        float4 v = ((const float4*)F)[idx];
        ushort4 r;
        r.x = f2bf(v.x); r.y = f2bf(v.y); r.z = f2bf(v.z); r.w = f2bf(v.w);
        ((ushort4*)Fb)[idx] = r;
    }
}

// ---------------- fused kernel: GEMM + histogram-of-exp + top-k + loss ----------------
// Grid = 256 blocks (one/CU), 1024 threads = 16 waves. Block owns 16 anchor
// rows x all 4096 cols; wave w sweeps cols [w*256, w*256+256).
// R15 changes vs R14:
//  - __launch_bounds__(1024, 4): LDS 70KB lets 2 blocks/CU fit, so the
//    compiler was budgeting 8 waves/SIMD -> 40 VGPRs -> latency-exposed
//    code (VALUBusy 23%, MfmaUtil 3%, HBM 1% = vmcnt stalls). Only 1 block
//    is ever resident; declare 4 waves/EU -> 128 VGPR budget.
//  - with the budget, 1-tile-ahead register prefetch (t-loop fully unrolled
//    so prefetch regs rename instead of copy): next tile's 8 loads issue
//    before this tile's MFMA+epilogue.
//  - tail reverted to rowout + reduce_kernel: the folded f64-atomic tail
//    (768 same-line device-scope RMWs) cost ~8us in R13/R14.
__global__ __launch_bounds__(1024, 4) void fused_all(const u16* __restrict__ Fb,
                                                     const int* __restrict__ labels,
                                                     float2* __restrict__ rowout) {
    __shared__ u64 hpk[16 * HBINS];            // 64 KB  [row][bin] packed (cnt<<40 | exp*2^30)
    __shared__ unsigned char labc[BSZ];        // 4 KB
    __shared__ float ps[16], pe[16], pc[16];

    const int tid  = threadIdx.x;
    const int wave = tid >> 6, lane = tid & 63;
    const int l16  = lane & 15, quad = lane >> 4;
    const int brow = blockIdx.x * 16;

    // ---- init ----
    {
        int4 lv = ((const int4*)labels)[tid];          // BSZ/4 == 1024 == blockDim
        uchar4 r;
        r.x = (unsigned char)lv.x; r.y = (unsigned char)lv.y;
        r.z = (unsigned char)lv.z; r.w = (unsigned char)lv.w;
        ((uchar4*)labc)[tid] = r;
    }
    #pragma unroll
    for (int q = 0; q < 8; ++q) hpk[q * 1024 + tid] = 0ull;
    if (tid < 16) { ps[tid] = 0.f; pe[tid] = 0.f; pc[tid] = 0.f; }
    __syncthreads();

    // ---- A fragments in registers for the whole sweep ----
    const u16* Ab = Fb + (size_t)(brow + l16) * DIM + quad * 8;
    bf16x8 afr[4];
    #pragma unroll
    for (int ks = 0; ks < 4; ++ks) afr[ks] = *(const bf16x8*)(Ab + ks * 32);

    unsigned char labr_[4];
    #pragma unroll
    for (int e = 0; e < 4; ++e) labr_[e] = labc[brow + quad * 4 + e];

    // register accumulators for positives (rows quad*4+e)
    float pps[4] = {0.f, 0.f, 0.f, 0.f};
    float ppe[4] = {0.f, 0.f, 0.f, 0.f};
    float ppc[4] = {0.f, 0.f, 0.f, 0.f};

    // ---- phase 1: sweep 8 n-tiles of 32 cols, 1 tile register-prefetched ----
    const u16* Bw = Fb + (size_t)(wave * 256 + l16) * DIM + quad * 8;
    bf16x8 cb0[4], cb1[4];
    #pragma unroll
    for (int ks = 0; ks < 4; ++ks) {
        cb0[ks] = *(const bf16x8*)(Bw + ks * 32);
        cb1[ks] = *(const bf16x8*)(Bw + 16 * DIM + ks * 32);
    }
    #pragma unroll
    for (int t = 0; t < 8; ++t) {
        bf16x8 nb0[4], nb1[4];
        if (t < 7) {                                   // prefetch next tile
            const u16* Bn = Bw + (size_t)(t + 1) * 32 * DIM;
            #pragma unroll
            for (int ks = 0; ks < 4; ++ks) {
                nb0[ks] = *(const bf16x8*)(Bn + ks * 32);
                nb1[ks] = *(const bf16x8*)(Bn + 16 * DIM + ks * 32);
            }
        }

        floatx4 a0 = (floatx4){0.f, 0.f, 0.f, 0.f};
        floatx4 a1 = (floatx4){0.f, 0.f, 0.f, 0.f};
        #pragma unroll
        for (int ks = 0; ks < 4; ++ks) {
            a0 = __builtin_amdgcn_mfma_f32_16x16x32_bf16(afr[ks], cb0[ks], a0, 0, 0, 0);
            a1 = __builtin_amdgcn_mfma_f32_16x16x32_bf16(afr[ks], cb1[ks], a1, 0, 0, 0);
        }

        // epilogue: C/D map col = l16 (B side), row = quad*4+e (A side) [m89/m91]
        const int tn0 = wave * 256 + t * 32;
        #pragma unroll
        for (int nt = 0; nt < 2; ++nt) {
            const floatx4 accv = nt ? a1 : a0;
            const int cg_ = tn0 + nt * 16 + l16;       // global col
            const int lc = labc[cg_];
            #pragma unroll
            for (int e = 0; e < 4; ++e) {
                const int rl = quad * 4 + e;
                const int rg = brow + rl;
                if (cg_ == rg) continue;               // diagonal
                const float s = accv[e];
                const bool pos = (lc == (int)labr_[e]);  // positive (~41/row total)
                if (pos | (s > TGUESS)) {
                    const float ex = __expf((s - 1.f) * 10.f);
                    if (pos) {                         // register accumulate
                        pps[e] += s; ppe[e] += ex; ppc[e] += 1.f;
                    } else {                           // hard negative -> packed histogram
                        int b = (int)((s - 0.1f) * 800.f);
                        b = b < 0 ? 0 : (b > HBINS - 1 ? HBINS - 1 : b);
                        const u64 pk = (1ull << 40) + (u64)(u32)(ex * EXPSCALE);
                        atomicAdd(&hpk[rl * HBINS + b], pk);   // fire-and-forget
                    }
                }
            }
        }

        if (t < 7) {
            #pragma unroll
            for (int ks = 0; ks < 4; ++ks) { cb0[ks] = nb0[ks]; cb1[ks] = nb1[ks]; }
        }
    }

    // ---- fold positive partials: reduce over the 16-lane l16 group, 1 atomic/row/wave ----
    #pragma unroll
    for (int e = 0; e < 4; ++e) {
        float a = pps[e], b = ppe[e], c = ppc[e];
        #pragma unroll
        for (int off = 8; off; off >>= 1) {
            a += __shfl_xor(a, off);
            b += __shfl_xor(b, off);
            c += __shfl_xor(c, off);
        }
        if (l16 == 0) {
            const int rl = quad * 4 + e;
            atomicAdd(&ps[rl], a);
            atomicAdd(&pe[rl], b);
            atomicAdd(&pc[rl], c);
        }
    }
    __syncthreads();

    // ---- phase 2: wave r = threshold bin + loss for row r (wave-private) ----
    {
        const int r = wave;
        const u64* hp = hpk + r * HBINS;

        int local[8], csum = 0;                        // lane owns bins [lane*8, lane*8+8)
        float lx[8];
        #pragma unroll
        for (int t2 = 0; t2 < 8; ++t2) {
            const u64 v = hp[lane * 8 + t2];
            local[t2] = (int)(v >> 40);
            lx[t2] = (float)(v & MASK40) * (1.0f / EXPSCALE);
            csum += local[t2];
        }
        int suf = csum;
        #pragma unroll
        for (int off = 1; off < 64; off <<= 1) {       // wave suffix-sum
            int t2 = __shfl_down(suf, off);
            if (lane + off < 64) suf += t2;
        }
        const int above = suf - csum;
        const bool owner = (above < K_TOP) && (suf >= K_TOP);
        int b1o = 0, c1o = 0;
        if (owner) {
            int acc2 = above;
            #pragma unroll
            for (int t2 = 7; t2 >= 0; --t2) {
                if (acc2 + local[t2] >= K_TOP) { b1o = lane * 8 + t2; c1o = acc2; break; }
                acc2 += local[t2];
            }
        }
        unsigned long long bm = __ballot(owner);
        int b1, K2;
        if (bm == 0ull) {            // fewer than K_TOP candidates: take them all
            b1 = -1; K2 = 0;
        } else {
            const int src = __ffsll((long long)bm) - 1;
            b1 = __shfl(b1o, src);
            K2 = K_TOP - __shfl(c1o, src);
        }

        float te = 0.f;                                // exact exp-sum above bin b1
        #pragma unroll
        for (int t2 = 0; t2 < 8; ++t2) {
            const int b = lane * 8 + t2;
            if (b > b1) te += lx[t2];
        }
        #pragma unroll
        for (int off = 32; off; off >>= 1) te += __shfl_down(te, off);

        if (lane == 0) {
            float tsum = 0.f;
            if (K2 > 0) {                              // K2>0 implies b1 >= 0
                const u64 v = hp[b1];
                const int cb = (int)(v >> 40);
                if (cb > 0)                            // in-bin average
                    tsum = (float)K2 * ((float)(v & MASK40) * (1.0f / EXPSCALE)) / (float)cb;
            }
            const float pcnt = pc[r];
            const int labi = labc[brow + r];
            float pr = 0.f, vd = 0.f;
            if (labi > 0 && pcnt > 0.f) {
                float denom = pe[r] + te + tsum;
                float slp = 10.f * (ps[r] - pcnt) - pcnt * logf(denom);
                pr = -2.f * slp / pcnt;
                vd = 1.f;
            }
            rowout[brow + r] = make_float2(pr, vd);
        }
    }
}

// ---------------- tree-reduce 4096 row results -> scalar ----------------
__global__ __launch_bounds__(256) void reduce_kernel(const float2* __restrict__ rowout,
                                                     float* __restrict__ out) {
    __shared__ float reda[4], redb[4];
    const int tid = threadIdx.x, lane = tid & 63, w = tid >> 6;
    float sa = 0.f, sb = 0.f;
    #pragma unroll
    for (int j = 0; j < 16; ++j) {
        float2 v = rowout[j * 256 + tid];
        sa += v.x; sb += v.y;
    }
    #pragma unroll
    for (int off = 32; off; off >>= 1) {
        sa += __shfl_down(sa, off);
        sb += __shfl_down(sb, off);
    }
    if (lane == 0) { reda[w] = sa; redb[w] = sb; }
    __syncthreads();
    if (tid == 0)
        out[0] = (reda[0] + reda[1] + reda[2] + reda[3]) /
                 (redb[0] + redb[1] + redb[2] + redb[3]);
}

extern "C" void kernel_launch(void* const* d_in, const int* in_sizes, int n_in,
                              void* d_out, int out_size, void* d_ws, size_t ws_size,
                              hipStream_t stream) {
    const float* F      = (const float*)d_in[0];
    const int*   labels = (const int*)d_in[1];
    float*       out    = (float*)d_out;

    char* w = (char*)d_ws;
    u16*    Fb     = (u16*)w;               w += (size_t)BSZ * DIM * 2;   // 1 MB
    float2* rowout = (float2*)w;            w += (size_t)BSZ * 8;         // 32 KB

    pre_kernel<<<512, 256, 0, stream>>>(F, Fb);
    fused_all<<<256, 1024, 0, stream>>>(Fb, labels, rowout);
    reduce_kernel<<<1, 256, 0, stream>>>(rowout, out);
}